// Round 1
// baseline (250.509 us; speedup 1.0000x reference)
//
#include <hip/hip_runtime.h>

// AR(24) rollout: out[b,t,d], t in [0,168), from last 24 timesteps of x[b,:,d].
// One thread per (b,d) scalar sequence; window in 24 registers, time loop in
// groups of ORDER so the sliding window is static register rotation.
//
// R2 lesson: dur_us includes ~214 us of harness 0xAA fills; kernel itself was
// ~23.4 us vs a 15.5 us memory floor (88 MB NT-stream write + 12.6 MB read).
// R3 theory: grid = BATCH*DIMS threads = 2048 waves = only 2 waves/SIMD ->
// compute (6.7 us issue) and store-drain (15.5 us) serialize instead of
// overlapping (23.4 ~= 6.7 + 15.5). Fix: 2x threads per sequence with
// bit-exact redundant compute. h=0 threads run groups 0..3 and store t<96;
// h=1 threads run the IDENTICAL chain through all 7 groups but store only
// t>=96. Same FMA order -> absmax stays 0.0. Compute rises 1.57x (10.6 us
// issue, still under the 15.5 us memory floor) while occupancy doubles to
// 4 waves/SIMD, letting FMA chains hide under the HBM write drain.

#define BATCH 256
#define SEQ   336
#define DIMS  512
#define ORDER 24
#define TSEQ  168
#define NGROUP  (TSEQ / ORDER)  // 7 groups of 24 steps
#define SPLIT_G 4               // h=0 stores groups [0,4); h=1 stores [4,7)

__global__ __launch_bounds__(256) void ar_rollout_kernel(
    const float* __restrict__ x,     // [BATCH, SEQ, DIMS]
    const float* __restrict__ W,     // [ORDER, 1]
    const float* __restrict__ bias,  // [1]
    float* __restrict__ out)         // [BATCH, TSEQ, DIMS]
{
    // blockIdx.x & 1 selects the t-half; pairs of blocks cover the same
    // (b,d) range so h is block-uniform (no divergence) and h0/h1 blocks
    // interleave across CUs/XCDs.
    const int h   = blockIdx.x & 1;
    const int tid = (blockIdx.x >> 1) * blockDim.x + threadIdx.x;  // b*DIMS + d
    const int d = tid & (DIMS - 1);
    const int b = tid >> 9;          // tid / DIMS
    if (b >= BATCH) return;

    // AR coefficients (wave-uniform -> scalar broadcasts) and bias.
    float wc[ORDER];
#pragma unroll
    for (int k = 0; k < ORDER; ++k) wc[k] = W[k];
    const float bb = bias[0];

    // Init window: x[b, SEQ-ORDER+k, d], k = 0..23 (oldest first).
    // Consecutive lanes = consecutive d -> each of the 24 loads is coalesced.
    const float* xp = x + ((size_t)b * SEQ + (SEQ - ORDER)) * DIMS + d;
    float w[ORDER];
#pragma unroll
    for (int k = 0; k < ORDER; ++k) w[k] = xp[(size_t)k * DIMS];

    // h=1: silent prefix — groups [0, SPLIT_G), bit-identical FMA chain,
    // no stores. Window w stays live (feeds the stored groups), so no DCE.
    if (h) {
#pragma unroll 1
        for (int g = 0; g < SPLIT_G; ++g) {
#pragma unroll
            for (int j = 0; j < ORDER; ++j) {
                float y = bb;
#pragma unroll
                for (int k = 0; k < ORDER; ++k)
                    y = fmaf(w[(j + k) % ORDER], wc[k], y);
                w[j] = y;
            }
        }
    }

    // Stored groups. At step j within a group, logical window element k lives
    // in physical register w[(j+k) % ORDER]; the new value overwrites w[j].
    // Serial FMA chain kept identical to R0 (absmax 0.0).
    const int g0 = h ? SPLIT_G : 0;
    const int g1 = h ? NGROUP  : SPLIT_G;
    float* op = out + ((size_t)b * TSEQ + (size_t)g0 * ORDER) * DIMS + d;
#pragma unroll 1
    for (int g = g0; g < g1; ++g) {
#pragma unroll
        for (int j = 0; j < ORDER; ++j) {
            float y = bb;
#pragma unroll
            for (int k = 0; k < ORDER; ++k)
                y = fmaf(w[(j + k) % ORDER], wc[k], y);
            w[j] = y;
            __builtin_nontemporal_store(y, op);  // streaming 88 MB, never re-read
            op += DIMS;
        }
    }
}

extern "C" void kernel_launch(void* const* d_in, const int* in_sizes, int n_in,
                              void* d_out, int out_size, void* d_ws, size_t ws_size,
                              hipStream_t stream) {
    const float* x    = (const float*)d_in[0];
    const float* W    = (const float*)d_in[1];
    const float* bias = (const float*)d_in[2];
    // d_in[3] is tar_seq_len (==168), compile-time constant here.
    float* out = (float*)d_out;

    const int threads = 256;
    const int blocks  = 2 * (BATCH * DIMS) / threads;  // 1024: 2 t-halves per (b,d) range
    ar_rollout_kernel<<<blocks, threads, 0, stream>>>(x, W, bias, out);
}

// Round 3
// 236.184 us; speedup vs baseline: 1.0606x; 1.0606x over previous
//
#include <hip/hip_runtime.h>

// AR(24) rollout: out[b,t,d], t in [0,168), from last 24 timesteps of x[b,:,d].
//
// R2 lesson: dur_us includes ~214 us of harness 0xAA fills; kernel itself was
// ~23.4 us vs a 15.5 us memory floor (88 MB NT-stream write + 12.6 MB read).
// R3 FAILED (+12.8 us): 2x redundant-compute split to double occupancy. The
// chain is NOT latency-bound (step j+1's first 23 FMAs are independent of
// step j's result -> compiler pipelines steps; compute is ~6.7 us pure
// issue). Redundant work just added issue time. Reverted.
// R4 theory: stores were global_store_dword (4 B/lane, 256 B/wave). The
// harness fill hits 6.5 TB/s write-only with dwordx4; our kernel sustained
// only ~4 TB/s. Fatten the write stream: 2 adjacent d per thread, float2
// (dwordx2) NT stores -> half the store instructions, 2x bytes in flight per
// wave (63-deep vmcnt cap). Each scalar sequence keeps the exact serial FMA
// order (two independent chains per thread) -> absmax stays 0.0.
// R5: compile fix — __builtin_nontemporal_store rejects HIP_vector_type
// float2; use clang ext_vector_type(2) float instead.

#define BATCH 256
#define SEQ   336
#define DIMS  512
#define ORDER 24
#define TSEQ  168

typedef float f32x2 __attribute__((ext_vector_type(2)));

__global__ __launch_bounds__(256) void ar_rollout_kernel(
    const float* __restrict__ x,     // [BATCH, SEQ, DIMS]
    const float* __restrict__ W,     // [ORDER, 1]
    const float* __restrict__ bias,  // [1]
    float* __restrict__ out)         // [BATCH, TSEQ, DIMS]
{
    // One thread per (b, d-pair): d = 2*p, covers {d, d+1}.
    const int tid = blockIdx.x * blockDim.x + threadIdx.x;  // b*(DIMS/2) + p
    const int p = tid & (DIMS / 2 - 1);
    const int b = tid >> 8;          // tid / (DIMS/2)
    if (b >= BATCH) return;
    const int d = p * 2;

    // AR coefficients (wave-uniform -> scalar broadcasts) and bias.
    float wc[ORDER];
#pragma unroll
    for (int k = 0; k < ORDER; ++k) wc[k] = W[k];
    const float bb = bias[0];

    // Init window: x[b, SEQ-ORDER+k, {d,d+1}], k = 0..23 (oldest first).
    // Consecutive lanes = consecutive float2 -> each load is a coalesced
    // 512 B/wave dwordx2 burst.
    const f32x2* xp = (const f32x2*)(x + ((size_t)b * SEQ + (SEQ - ORDER)) * DIMS + d);
    f32x2 w[ORDER];
#pragma unroll
    for (int k = 0; k < ORDER; ++k) w[k] = xp[(size_t)k * (DIMS / 2)];

    // Rollout. At step j within a group, logical window element k lives in
    // physical register w[(j+k) % ORDER]; the new value overwrites w[j].
    // Two independent serial chains (x,y components), each with the exact
    // R0 FMA order (absmax 0.0); 2-way ILP keeps FMA issue dense.
    f32x2* op = (f32x2*)(out + (size_t)b * TSEQ * DIMS + d);
#pragma unroll 1
    for (int g = 0; g < TSEQ / ORDER; ++g) {
#pragma unroll
        for (int j = 0; j < ORDER; ++j) {
            float ya = bb;
            float yb = bb;
#pragma unroll
            for (int k = 0; k < ORDER; ++k) {
                const f32x2 wk = w[(j + k) % ORDER];
                ya = fmaf(wk.x, wc[k], ya);
                yb = fmaf(wk.y, wc[k], yb);
            }
            f32x2 y2;
            y2.x = ya;
            y2.y = yb;
            w[j] = y2;
            __builtin_nontemporal_store(y2, op);  // 88 MB stream, never re-read
            op += DIMS / 2;
        }
    }
}

extern "C" void kernel_launch(void* const* d_in, const int* in_sizes, int n_in,
                              void* d_out, int out_size, void* d_ws, size_t ws_size,
                              hipStream_t stream) {
    const float* x    = (const float*)d_in[0];
    const float* W    = (const float*)d_in[1];
    const float* bias = (const float*)d_in[2];
    // d_in[3] is tar_seq_len (==168), compile-time constant here.
    float* out = (float*)d_out;

    const int threads = 256;
    const int blocks  = (BATCH * DIMS / 2) / threads;  // 256 blocks, 1/CU
    ar_rollout_kernel<<<blocks, threads, 0, stream>>>(x, W, bias, out);
}